// Round 1
// baseline (217.595 us; speedup 1.0000x reference)
//
#include <hip/hip_runtime.h>
#include <math.h>

#define KBINS 64
#define PARAM_DIM 255
#define HID 32
#define BOUND 3.0f
#define MIN_W 0.001f
#define MIN_H 0.001f
#define MIN_D 0.001f

// Transpose W2 (32x32) and W3 (32x255) so that output-columns are contiguous.
// w3t[j*32 + i] = W3[i*255 + j]   (j = param column, i = hidden index)
// w2t[j*32 + i] = W2[i*32 + j]
__global__ void prep_kernel(const float* __restrict__ W2, const float* __restrict__ W3,
                            float* __restrict__ w2t, float* __restrict__ w3t) {
    int tid = blockIdx.x * blockDim.x + threadIdx.x;
    int nth = gridDim.x * blockDim.x;
    for (int k = tid; k < PARAM_DIM * HID; k += nth) {
        int j = k >> 5, i = k & 31;
        w3t[k] = W3[i * PARAM_DIM + j];
    }
    for (int k = tid; k < HID * HID; k += nth) {
        int j = k >> 5, i = k & 31;
        w2t[k] = W2[i * HID + j];
    }
}

__global__ __launch_bounds__(256) void spline_kernel(
    const float* __restrict__ x_in, const float* __restrict__ cond_in,
    const float* __restrict__ W1, const float* __restrict__ b1,
    const float* __restrict__ b2, const float* __restrict__ b3,
    const float* __restrict__ w2t, const float* __restrict__ w3t,
    float* __restrict__ out, int N) {

    // LDS copy of param columns 127..254 (d_un and l_un region), padded
    // stride 33 floats so per-lane dynamic column reads spread across banks.
    __shared__ float sdl[128 * 33];
    for (int k = threadIdx.x; k < 128 * HID; k += 256) {
        int c = k >> 5, i = k & 31;
        sdl[c * 33 + i] = w3t[(127 + c) * HID + i];
    }
    __syncthreads();

    int gid = blockIdx.x * 256 + threadIdx.x;
    if (gid >= N) return;

    // ---- MLP: h2 = relu(relu(cx*W1+b1) @ W2 + b2)
    float cx = cond_in[gid];
    float h2[HID];
    {
        float h1[HID];
#pragma unroll
        for (int k = 0; k < HID; k++) h1[k] = fmaxf(fmaf(cx, W1[k], b1[k]), 0.f);
#pragma unroll
        for (int j = 0; j < HID; j++) {
            float acc = b2[j];
#pragma unroll
            for (int k = 0; k < HID; k++) acc = fmaf(h1[k], w2t[j * HID + k], acc);
            h2[j] = fmaxf(acc, 0.f);
        }
    }

    float x = x_in[gid];
    bool inside = (x >= -BOUND) && (x <= BOUND);
    float xc = fminf(fmaxf(x, -BOUND), BOUND);

    float arr[KBINS];

    // ---- W pass: w_un = params[:, 0:64]
#pragma unroll
    for (int j = 0; j < KBINS; j++) {
        float acc = b3[j];
#pragma unroll
        for (int k = 0; k < HID; k++) acc = fmaf(h2[k], w3t[j * HID + k], acc);
        arr[j] = acc;
    }
    float mx = arr[0];
#pragma unroll
    for (int j = 1; j < KBINS; j++) mx = fmaxf(mx, arr[j]);
    float tot = 0.f;
#pragma unroll
    for (int j = 0; j < KBINS; j++) {
        arr[j] = __expf(arr[j] - mx);
        tot += arr[j];
    }
    float coefw = (1.0f - MIN_W * (float)KBINS) / tot;

    // ---- scan boundaries: cum[t] = 2B*(MIN_W*t + coefw*S_t) - B, find bin
    int idx = 63;
    float xk = -BOUND, xk1 = BOUND;
    float bprev = -BOUND;
    bool found = false;
    float S = 0.f;
#pragma unroll
    for (int t = 1; t <= 63; t++) {
        S += arr[t - 1];
        float cur = fmaf(2.0f * BOUND, fmaf(coefw, S, MIN_W * (float)t), -BOUND);
        bool hit = (!found) && (xc < cur);
        if (hit) { idx = t - 1; xk = bprev; xk1 = cur; found = true; }
        bprev = cur;
    }
    if (!found) { idx = 63; xk = bprev; xk1 = BOUND; }
    float wk = xk1 - xk;

    // ---- H pass: h_un = params[:, 64:128]
#pragma unroll
    for (int j = 0; j < KBINS; j++) {
        float acc = b3[KBINS + j];
#pragma unroll
        for (int k = 0; k < HID; k++) acc = fmaf(h2[k], w3t[(KBINS + j) * HID + k], acc);
        arr[j] = acc;
    }
    float mxh = arr[0];
#pragma unroll
    for (int j = 1; j < KBINS; j++) mxh = fmaxf(mxh, arr[j]);
    float toth = 0.f, Sh = 0.f, eidx = 0.f;
#pragma unroll
    for (int j = 0; j < KBINS; j++) {
        float e = __expf(arr[j] - mxh);
        toth += e;
        Sh += (j < idx) ? e : 0.f;
        eidx = (j == idx) ? e : eidx;
    }
    float coefh = (1.0f - MIN_H * (float)KBINS) / toth;
    float yk = fmaf(2.0f * BOUND, fmaf(coefh, Sh, MIN_H * (float)idx), -BOUND);
    float hk = (idx == 63) ? (BOUND - yk)
                           : 2.0f * BOUND * fmaf(coefh, eidx, MIN_H);

    // ---- dynamic columns: d_un[idx-1], d_un[idx], l_un[idx] from LDS
    // sdl column c holds param column 127+c.
    float accd0 = b3[127 + idx];   // derivs[idx]   (if idx>0)
    float accd1 = b3[128 + idx];   // derivs[idx+1] (if idx<63)
    float accl  = b3[191 + idx];   // l_un[idx]
    const float* c0 = &sdl[idx * 33];
    const float* c1 = &sdl[(idx + 1) * 33];
    const float* cl = &sdl[(64 + idx) * 33];
#pragma unroll
    for (int k = 0; k < HID; k++) {
        accd0 = fmaf(h2[k], c0[k], accd0);
        accd1 = fmaf(h2[k], c1[k], accd1);
        accl  = fmaf(h2[k], cl[k], accl);
    }

    float sp0 = fmaxf(accd0, 0.f) + __logf(1.f + __expf(-fabsf(accd0)));
    float sp1 = fmaxf(accd1, 0.f) + __logf(1.f + __expf(-fabsf(accd1)));
    float d0 = (idx == 0)  ? 1.f : (MIN_D + sp0);
    float d1 = (idx == 63) ? 1.f : (MIN_D + sp1);
    float lam = fmaf(0.95f, 1.f / (1.f + __expf(-accl)), 0.025f);

    float slope = hk / wk;
    float wb = sqrtf(d0 / d1);
    float wc = fmaf(lam, d0, (1.f - lam) * wb * d1) / slope;
    float ya = yk, yb = yk + hk;
    float yc = ((1.f - lam) * ya + lam * wb * yb) / ((1.f - lam) + lam * wb);
    float theta = (xc - xk) / wk;
    bool left = theta <= lam;
    float num = left ? (ya * (lam - theta) + wc * yc * theta)
                     : (wc * yc * (1.f - theta) + wb * yb * (theta - lam));
    float den = left ? ((lam - theta) + wc * theta)
                     : (wc * (1.f - theta) + wb * (theta - lam));
    float y_in = num / den;
    float dnum = left ? (wc * lam * (yc - ya))
                      : (wb * wc * (1.f - lam) * (yb - yc));
    float ld_in = __logf(dnum) - 2.f * __logf(fabsf(den)) - __logf(wk);

    out[gid]     = inside ? y_in : x;
    out[N + gid] = inside ? ld_in : 0.f;
}

extern "C" void kernel_launch(void* const* d_in, const int* in_sizes, int n_in,
                              void* d_out, int out_size, void* d_ws, size_t ws_size,
                              hipStream_t stream) {
    const float* x  = (const float*)d_in[0];
    const float* cx = (const float*)d_in[1];
    const float* W1 = (const float*)d_in[2];
    const float* b1 = (const float*)d_in[3];
    const float* W2 = (const float*)d_in[4];
    const float* b2 = (const float*)d_in[5];
    const float* W3 = (const float*)d_in[6];
    const float* b3 = (const float*)d_in[7];
    int N = in_sizes[0];

    float* w3t = (float*)d_ws;                 // 255*32 floats
    float* w2t = w3t + PARAM_DIM * HID;        // 32*32 floats
    float* out = (float*)d_out;

    hipLaunchKernelGGL(prep_kernel, dim3(34), dim3(256), 0, stream, W2, W3, w2t, w3t);
    hipLaunchKernelGGL(spline_kernel, dim3((N + 255) / 256), dim3(256), 0, stream,
                       x, cx, W1, b1, b2, b3, w2t, w3t, out, N);
}

// Round 2
// 206.574 us; speedup vs baseline: 1.0533x; 1.0533x over previous
//
#include <hip/hip_runtime.h>
#include <math.h>

#define KBINS 64
#define PARAM_DIM 255
#define HID 32
#define BOUND 3.0f
#define LOG2E 1.4426950408889634f
#define LN2 0.6931471805599453f

typedef float f2 __attribute__((ext_vector_type(2)));

__device__ __forceinline__ float fexp2(float x) { return __builtin_amdgcn_exp2f(x); }
__device__ __forceinline__ float flog2(float x) { return __builtin_amdgcn_logf(x); }
__device__ __forceinline__ float frcp(float x)  { return __builtin_amdgcn_rcpf(x); }

// Transpose + prescale. w3t[j*32+i] = W3[i*255+j] * (j<128 ? log2e : 1)
// (softmax is invariant under logit base-change; lets us use v_exp_f32 directly)
__global__ void prep_kernel(const float* __restrict__ W2, const float* __restrict__ W3,
                            const float* __restrict__ b3,
                            float* __restrict__ w2t, float* __restrict__ w3t,
                            float* __restrict__ b3s) {
    int tid = blockIdx.x * blockDim.x + threadIdx.x;
    int nth = gridDim.x * blockDim.x;
    for (int k = tid; k < PARAM_DIM * HID; k += nth) {
        int j = k >> 5, i = k & 31;
        float s = (j < 128) ? LOG2E : 1.f;
        w3t[k] = W3[i * PARAM_DIM + j] * s;
    }
    for (int k = tid; k < HID * HID; k += nth) {
        int j = k >> 5, i = k & 31;
        w2t[k] = W2[i * HID + j];
    }
    for (int k = tid; k < PARAM_DIM; k += nth) {
        float s = (k < 128) ? LOG2E : 1.f;
        b3s[k] = b3[k] * s;
    }
}

__global__ __launch_bounds__(256, 2) void spline_kernel(
    const float* __restrict__ x_in, const float* __restrict__ cond_in,
    const float* __restrict__ W1, const float* __restrict__ b1,
    const float* __restrict__ b2, const float* __restrict__ b3s,
    const float* __restrict__ w2t, const float* __restrict__ w3t,
    float* __restrict__ out, int N) {

    // LDS: param columns 127..254 (d_un, l_un region), stride 34 floats
    // (8B-aligned for ds_read_b64, odd-16 to spread banks), plus their biases.
    __shared__ float sdl[128 * 34 + 128];
    for (int k = threadIdx.x; k < 128 * HID; k += 256) {
        int c = k >> 5, i = k & 31;
        sdl[c * 34 + i] = w3t[(127 + c) * HID + i];
    }
    for (int c = threadIdx.x; c < 128; c += 256) sdl[128 * 34 + c] = b3s[127 + c];
    __syncthreads();

    int gid = blockIdx.x * 256 + threadIdx.x;
    if (gid >= N) return;

    // ---- MLP: h2 = relu(relu(cx*W1+b1) @ W2 + b2)
    float cx = cond_in[gid];
    float h2[HID];
    {
        float h1[HID];
#pragma unroll
        for (int k = 0; k < HID; k++) h1[k] = fmaxf(fmaf(cx, W1[k], b1[k]), 0.f);
#pragma unroll
        for (int j = 0; j < HID; j++) {
            float acc = b2[j];
#pragma unroll
            for (int k = 0; k < HID; k++) acc = fmaf(h1[k], w2t[j * HID + k], acc);
            h2[j] = fmaxf(acc, 0.f);
        }
    }

    float x = x_in[gid];
    bool inside = (x >= -BOUND) && (x <= BOUND);
    float xc = fminf(fmaxf(x, -BOUND), BOUND);

    float arr[KBINS];

    // ---- W logits (log2-domain)
#pragma unroll
    for (int j = 0; j < KBINS; j++) {
        float acc = b3s[j];
#pragma unroll
        for (int k = 0; k < HID; k++) acc = fmaf(h2[k], w3t[j * HID + k], acc);
        arr[j] = acc;
    }
    float mx = fmaxf(arr[0], arr[1]);
#pragma unroll
    for (int j = 2; j < KBINS; j += 2) mx = fmaxf(fmaxf(arr[j], arr[j + 1]), mx);
    float tot = 0.f;
#pragma unroll
    for (int j = 0; j < KBINS; j++) {
        float e = fexp2(arr[j] - mx);
        arr[j] = e;
        tot += e;
    }

    // ---- bin scan, denominator-free condition:
    // cum_t <= xc  <=>  5.616*S_t <= (xc+3-0.006t)*tot
    float a = (xc + BOUND) * tot;
    float d = 0.006f * tot;
    float P = 0.f, Pk = 0.f, ek = arr[0], r = a;
    int idx = 0;
#pragma unroll
    for (int t = 1; t <= 63; t++) {
        P = fmaf(5.616f, arr[t - 1], P);
        r -= d;
        bool c = (P <= r);
        idx += c ? 1 : 0;
        Pk = c ? P : Pk;
        ek = c ? arr[t] : ek;
    }
    float rcptot = frcp(tot);
    float idxf = (float)idx;
    float xk = fmaf(0.006f, idxf, -BOUND) + Pk * rcptot;
    float wk = fmaf(5.616f * rcptot, ek, 0.006f);
    wk = (idx == 63) ? (BOUND - xk) : wk;

    // ---- H logits (reuse arr) + fused single-pass selection
#pragma unroll
    for (int j = 0; j < KBINS; j++) {
        float acc = b3s[KBINS + j];
#pragma unroll
        for (int k = 0; k < HID; k++) acc = fmaf(h2[k], w3t[(KBINS + j) * HID + k], acc);
        arr[j] = acc;
    }
    float mh = fmaxf(arr[0], arr[1]);
#pragma unroll
    for (int j = 2; j < KBINS; j += 2) mh = fmaxf(fmaxf(arr[j], arr[j + 1]), mh);
    float toth = 0.f, Sh = 0.f, eidx = 0.f;
#pragma unroll
    for (int j = 0; j < KBINS; j++) {
        float e = fexp2(arr[j] - mh);
        toth += e;
        Sh += (j < idx) ? e : 0.f;
        eidx = (j == idx) ? e : eidx;
    }
    float ch = 5.616f * frcp(toth);
    float yk = fmaf(0.006f, idxf, -BOUND) + ch * Sh;
    float hk = fmaf(ch, eidx, 0.006f);
    hk = (idx == 63) ? (BOUND - yk) : hk;

    // ---- dynamic columns from LDS (pairwise ds_read_b64)
    const float* c0 = &sdl[idx * 34];
    const float* c1 = c0 + 34;
    const float* cl = &sdl[(64 + idx) * 34];
    float accd0 = sdl[128 * 34 + idx];
    float accd1 = sdl[128 * 34 + idx + 1];
    float accl  = sdl[128 * 34 + 64 + idx];
#pragma unroll
    for (int k = 0; k < 16; k++) {
        f2 v0 = *(const f2*)(c0 + 2 * k);
        f2 v1 = *(const f2*)(c1 + 2 * k);
        f2 vl = *(const f2*)(cl + 2 * k);
        accd0 = fmaf(h2[2 * k], v0.x, accd0);
        accd0 = fmaf(h2[2 * k + 1], v0.y, accd0);
        accd1 = fmaf(h2[2 * k], v1.x, accd1);
        accd1 = fmaf(h2[2 * k + 1], v1.y, accd1);
        accl  = fmaf(h2[2 * k], vl.x, accl);
        accl  = fmaf(h2[2 * k + 1], vl.y, accl);
    }

    // softplus(v) = max(v,0) + ln2*log2(1+2^(-|v|*log2e))
    float t0 = fexp2(-fabsf(accd0) * LOG2E);
    float sp0 = fmaxf(accd0, 0.f) + LN2 * flog2(1.f + t0);
    float t1 = fexp2(-fabsf(accd1) * LOG2E);
    float sp1 = fmaxf(accd1, 0.f) + LN2 * flog2(1.f + t1);
    float d0 = (idx == 0)  ? 1.f : (0.001f + sp0);
    float d1 = (idx == 63) ? 1.f : (0.001f + sp1);
    float sig = frcp(1.f + fexp2(-accl * LOG2E));
    float lam = fmaf(0.95f, sig, 0.025f);

    float rwk = frcp(wk);
    float wb = sqrtf(d0 * frcp(d1));
    float wc = fmaf(lam, d0, (1.f - lam) * wb * d1) * wk * frcp(hk); // (..)/slope
    float ya = yk, yb = yk + hk;
    float yc = fmaf(1.f - lam, ya, lam * wb * yb) * frcp(fmaf(lam, wb, 1.f - lam));
    float theta = (xc - xk) * rwk;
    bool left = theta <= lam;
    float num = left ? fmaf(ya, lam - theta, wc * yc * theta)
                     : fmaf(wc * yc, 1.f - theta, wb * yb * (theta - lam));
    float den = left ? fmaf(wc, theta, lam - theta)
                     : fmaf(wc, 1.f - theta, wb * (theta - lam));
    float y_in = num * frcp(den);
    float dnum = left ? (wc * lam * (yc - ya))
                      : (wb * wc * (1.f - lam) * (yb - yc));
    float ld_in = LN2 * (flog2(dnum) - 2.f * flog2(fabsf(den)) - flog2(wk));

    out[gid]     = inside ? y_in : x;
    out[N + gid] = inside ? ld_in : 0.f;
}

extern "C" void kernel_launch(void* const* d_in, const int* in_sizes, int n_in,
                              void* d_out, int out_size, void* d_ws, size_t ws_size,
                              hipStream_t stream) {
    const float* x  = (const float*)d_in[0];
    const float* cx = (const float*)d_in[1];
    const float* W1 = (const float*)d_in[2];
    const float* b1 = (const float*)d_in[3];
    const float* W2 = (const float*)d_in[4];
    const float* b2 = (const float*)d_in[5];
    const float* W3 = (const float*)d_in[6];
    const float* b3 = (const float*)d_in[7];
    int N = in_sizes[0];

    float* w3t = (float*)d_ws;                  // 255*32
    float* w2t = w3t + PARAM_DIM * HID;         // 32*32
    float* b3s = w2t + HID * HID;               // 255
    float* out = (float*)d_out;

    hipLaunchKernelGGL(prep_kernel, dim3(34), dim3(256), 0, stream, W2, W3, b3, w2t, w3t, b3s);
    hipLaunchKernelGGL(spline_kernel, dim3((N + 255) / 256), dim3(256), 0, stream,
                       x, cx, W1, b1, b2, b3s, w2t, w3t, out, N);
}

// Round 3
// 88.297 us; speedup vs baseline: 2.4644x; 2.3395x over previous
//
#include <hip/hip_runtime.h>
#include <math.h>

#define BOUND 3.0f
#define LOG2E 1.4426950408889634f
#define LN2 0.6931471805599453f

typedef _Float16 half8 __attribute__((ext_vector_type(8)));
typedef _Float16 half4 __attribute__((ext_vector_type(4)));
typedef float f32x4 __attribute__((ext_vector_type(4)));

__device__ __forceinline__ float fexp2(float x) { return __builtin_amdgcn_exp2f(x); }
__device__ __forceinline__ float flog2(float x) { return __builtin_amdgcn_logf(x); }
__device__ __forceinline__ float frcp(float x)  { return __builtin_amdgcn_rcpf(x); }

#define LWAIT() do { asm volatile("s_waitcnt lgkmcnt(0)" ::: "memory"); \
                     __builtin_amdgcn_sched_barrier(0); } while (0)

// Pack A-fragments (M-side = weights, transposed GEMM: C[param][elem]).
// A-frag layout (16x16x32 f16): lane l holds A row (l&15), k = 8*(l>>4)+t.
// aW3[m][l][t] = W3[8*(l>>4)+t][16m + (l&15)] * (m<8 ? LOG2E : 1)   (col>=255 -> 0)
// aW2[m][l][t] = W2[8*(l>>4)+t][16m + (l&15)]
// b3s[i] = b3[i] * (i<128 ? LOG2E : 1)
__global__ void prep_kernel(const float* __restrict__ W2, const float* __restrict__ W3,
                            const float* __restrict__ b3,
                            _Float16* __restrict__ aW2, _Float16* __restrict__ aW3,
                            float* __restrict__ b3s) {
    int tid = blockIdx.x * blockDim.x + threadIdx.x;
    int nth = gridDim.x * blockDim.x;
    for (int i = tid; i < 16 * 64 * 8; i += nth) {
        int t = i & 7, l = (i >> 3) & 63, m = i >> 9;
        int k = 8 * (l >> 4) + t, col = 16 * m + (l & 15);
        float v = (col < 255) ? W3[k * 255 + col] : 0.f;
        if (m < 8) v *= LOG2E;
        aW3[i] = (_Float16)v;
    }
    for (int i = tid; i < 2 * 64 * 8; i += nth) {
        int t = i & 7, l = (i >> 3) & 63, m = i >> 9;
        int k = 8 * (l >> 4) + t, col = 16 * m + (l & 15);
        aW2[i] = (_Float16)W2[k * 32 + col];
    }
    for (int i = tid; i < 255; i += nth)
        b3s[i] = b3[i] * ((i < 128) ? LOG2E : 1.f);
}

__global__ __launch_bounds__(256, 2) void spline_kernel(
    const float* __restrict__ x_in, const float* __restrict__ cond_in,
    const float* __restrict__ W1, const float* __restrict__ b1,
    const float* __restrict__ b2, const float* __restrict__ b3s_g,
    const _Float16* __restrict__ aW2, const _Float16* __restrict__ aW3,
    float* __restrict__ out, int N) {

    __shared__ float scx[256];
    __shared__ float sb3[256];
    __shared__ float sb2[32];
    __shared__ float sbuf[4][64 * 68];   // per-wave scratch: 17408 B each

    const int tid = threadIdx.x;
    const int w = tid >> 6, l = tid & 63, j = l & 15, g = l >> 4;
    const int gown = blockIdx.x * 256 + tid;   // own element (thread-view)
    const int ic = (gown < N) ? gown : (N - 1);

    scx[tid] = cond_in[ic];
    if (tid < 255) sb3[tid] = b3s_g[tid];
    if (tid < 32) sb2[tid] = b2[tid];

    float x = x_in[ic];

    __syncthreads();

    float* buf = sbuf[w];
    _Float16* h2hi = (_Float16*)buf;                 // [64 elem][40 f16]
    _Float16* h2lo = (_Float16*)buf + 64 * 40;

    // ---------------- Phase 1: h1 B-fragments (rank-1, built in-layout) ----
    float4 w1a = *(const float4*)(W1 + 8 * g);
    float4 w1b = *(const float4*)(W1 + 8 * g + 4);
    float4 b1a = *(const float4*)(b1 + 8 * g);
    float4 b1b = *(const float4*)(b1 + 8 * g + 4);

    half8 h1hi[4], h1lo[4];
#pragma unroll
    for (int n = 0; n < 4; n++) {
        float c = scx[w * 64 + 16 * n + j];
        float h[8];
        h[0] = fmaxf(fmaf(c, w1a.x, b1a.x), 0.f);
        h[1] = fmaxf(fmaf(c, w1a.y, b1a.y), 0.f);
        h[2] = fmaxf(fmaf(c, w1a.z, b1a.z), 0.f);
        h[3] = fmaxf(fmaf(c, w1a.w, b1a.w), 0.f);
        h[4] = fmaxf(fmaf(c, w1b.x, b1b.x), 0.f);
        h[5] = fmaxf(fmaf(c, w1b.y, b1b.y), 0.f);
        h[6] = fmaxf(fmaf(c, w1b.z, b1b.z), 0.f);
        h[7] = fmaxf(fmaf(c, w1b.w, b1b.w), 0.f);
#pragma unroll
        for (int t = 0; t < 8; t++) {
            _Float16 hi = (_Float16)h[t];
            h1hi[n][t] = hi;
            h1lo[n][t] = (_Float16)(h[t] - (float)hi);
        }
    }

    // ---------------- Phase 2: MLP2 via MFMA, split h2, stage to LDS -------
    half8 a2[2];
    a2[0] = *(const half8*)(aW2 + (0 * 64 + l) * 8);
    a2[1] = *(const half8*)(aW2 + (1 * 64 + l) * 8);

#pragma unroll
    for (int m = 0; m < 2; m++) {
        float4 bb = *(const float4*)(sb2 + 16 * m + 4 * g);
#pragma unroll
        for (int n = 0; n < 4; n++) {
            f32x4 acc = {0.f, 0.f, 0.f, 0.f};
            acc = __builtin_amdgcn_mfma_f32_16x16x32_f16(a2[m], h1lo[n], acc, 0, 0, 0);
            acc = __builtin_amdgcn_mfma_f32_16x16x32_f16(a2[m], h1hi[n], acc, 0, 0, 0);
            float v0 = fmaxf(acc[0] + bb.x, 0.f);
            float v1 = fmaxf(acc[1] + bb.y, 0.f);
            float v2 = fmaxf(acc[2] + bb.z, 0.f);
            float v3 = fmaxf(acc[3] + bb.w, 0.f);
            _Float16 p0 = (_Float16)v0, p1 = (_Float16)v1, p2 = (_Float16)v2, p3 = (_Float16)v3;
            half4 hv = {p0, p1, p2, p3};
            half4 lv = {(_Float16)(v0 - (float)p0), (_Float16)(v1 - (float)p1),
                        (_Float16)(v2 - (float)p2), (_Float16)(v3 - (float)p3)};
            int off = (16 * n + j) * 40 + 16 * m + 4 * g;
            *(half4*)(h2hi + off) = hv;
            *(half4*)(h2lo + off) = lv;
        }
    }
    LWAIT();

    // ---------------- Phase 3: load h2 B-fragments ------------------------
    half8 bhi[4], blo[4];
#pragma unroll
    for (int n = 0; n < 4; n++) {
        bhi[n] = *(const half8*)(h2hi + (16 * n + j) * 40 + 8 * g);
        blo[n] = *(const half8*)(h2lo + (16 * n + j) * 40 + 8 * g);
    }
    LWAIT();   // frag reads returned; safe to overwrite buf below

    // ---------------- Phase 4: W logits (params 0..63), exp, stage --------
    {
        f32x4 cw[4][4];
#pragma unroll
        for (int m = 0; m < 4; m++) {
            half8 a = *(const half8*)(aW3 + (m * 64 + l) * 8);
            float4 bb = *(const float4*)(sb3 + 16 * m + 4 * g);
#pragma unroll
            for (int n = 0; n < 4; n++) {
                f32x4 acc = {0.f, 0.f, 0.f, 0.f};
                acc = __builtin_amdgcn_mfma_f32_16x16x32_f16(a, blo[n], acc, 0, 0, 0);
                acc = __builtin_amdgcn_mfma_f32_16x16x32_f16(a, bhi[n], acc, 0, 0, 0);
                acc[0] += bb.x; acc[1] += bb.y; acc[2] += bb.z; acc[3] += bb.w;
                cw[m][n] = acc;
            }
        }
        float mxn[4];
#pragma unroll
        for (int n = 0; n < 4; n++) {
            float mm = fmaxf(fmaxf(cw[0][n][0], cw[0][n][1]), fmaxf(cw[0][n][2], cw[0][n][3]));
#pragma unroll
            for (int m = 1; m < 4; m++)
                mm = fmaxf(mm, fmaxf(fmaxf(cw[m][n][0], cw[m][n][1]), fmaxf(cw[m][n][2], cw[m][n][3])));
            mm = fmaxf(mm, __shfl_xor(mm, 16));
            mm = fmaxf(mm, __shfl_xor(mm, 32));
            mxn[n] = mm;
        }
#pragma unroll
        for (int m = 0; m < 4; m++)
#pragma unroll
            for (int n = 0; n < 4; n++) {
                f32x4 e;
                e[0] = fexp2(cw[m][n][0] - mxn[n]);
                e[1] = fexp2(cw[m][n][1] - mxn[n]);
                e[2] = fexp2(cw[m][n][2] - mxn[n]);
                e[3] = fexp2(cw[m][n][3] - mxn[n]);
                *(f32x4*)(buf + (16 * n + j) * 68 + 16 * m + 4 * g) = e;
            }
    }
    LWAIT();

    // ---------------- Phase 5: per-thread W scan (row = own element) ------
    bool inside = (x >= -BOUND) && (x <= BOUND);
    float xc = fminf(fmaxf(x, -BOUND), BOUND);

    float ev[64];
#pragma unroll
    for (int t = 0; t < 16; t++) {
        f32x4 v = *(const f32x4*)(buf + l * 68 + 4 * t);
        ev[4 * t] = v[0]; ev[4 * t + 1] = v[1]; ev[4 * t + 2] = v[2]; ev[4 * t + 3] = v[3];
    }
    float s0 = 0.f, s1 = 0.f, s2 = 0.f, s3 = 0.f;
#pragma unroll
    for (int t = 0; t < 16; t++) {
        s0 += ev[4 * t]; s1 += ev[4 * t + 1]; s2 += ev[4 * t + 2]; s3 += ev[4 * t + 3];
    }
    float tot = (s0 + s1) + (s2 + s3);

    float aa = (xc + BOUND) * tot;
    float dd = 0.006f * tot;
    float P = 0.f, Pk = 0.f, r = aa;
    int idx = 0;
#pragma unroll
    for (int t = 1; t <= 63; t++) {
        P = fmaf(5.616f, ev[t - 1], P);
        r -= dd;
        bool c = (P <= r);
        idx += c ? 1 : 0;
        Pk = c ? P : Pk;
    }
    float ek = buf[l * 68 + idx];
    float rcptot = frcp(tot);
    float idxf = (float)idx;
    float xk = fmaf(0.006f, idxf, -BOUND) + Pk * rcptot;
    float wk = fmaf(5.616f * rcptot, ek, 0.006f);
    wk = (idx == 63) ? (BOUND - xk) : wk;
    LWAIT();   // scan reads done; safe to overwrite buf with H

    // ---------------- Phase 6: H logits (params 64..127), exp, stage ------
    {
        f32x4 ch[4][4];
#pragma unroll
        for (int m = 0; m < 4; m++) {
            half8 a = *(const half8*)(aW3 + ((m + 4) * 64 + l) * 8);
            float4 bb = *(const float4*)(sb3 + 64 + 16 * m + 4 * g);
#pragma unroll
            for (int n = 0; n < 4; n++) {
                f32x4 acc = {0.f, 0.f, 0.f, 0.f};
                acc = __builtin_amdgcn_mfma_f32_16x16x32_f16(a, blo[n], acc, 0, 0, 0);
                acc = __builtin_amdgcn_mfma_f32_16x16x32_f16(a, bhi[n], acc, 0, 0, 0);
                acc[0] += bb.x; acc[1] += bb.y; acc[2] += bb.z; acc[3] += bb.w;
                ch[m][n] = acc;
            }
        }
        float mxn[4];
#pragma unroll
        for (int n = 0; n < 4; n++) {
            float mm = fmaxf(fmaxf(ch[0][n][0], ch[0][n][1]), fmaxf(ch[0][n][2], ch[0][n][3]));
#pragma unroll
            for (int m = 1; m < 4; m++)
                mm = fmaxf(mm, fmaxf(fmaxf(ch[m][n][0], ch[m][n][1]), fmaxf(ch[m][n][2], ch[m][n][3])));
            mm = fmaxf(mm, __shfl_xor(mm, 16));
            mm = fmaxf(mm, __shfl_xor(mm, 32));
            mxn[n] = mm;
        }
#pragma unroll
        for (int m = 0; m < 4; m++)
#pragma unroll
            for (int n = 0; n < 4; n++) {
                f32x4 e;
                e[0] = fexp2(ch[m][n][0] - mxn[n]);
                e[1] = fexp2(ch[m][n][1] - mxn[n]);
                e[2] = fexp2(ch[m][n][2] - mxn[n]);
                e[3] = fexp2(ch[m][n][3] - mxn[n]);
                *(f32x4*)(buf + (16 * n + j) * 68 + 16 * m + 4 * g) = e;
            }
    }
    LWAIT();

    // ---------------- Phase 7: per-thread H selection ---------------------
    float t0 = 0.f, t1 = 0.f, t2 = 0.f, t3 = 0.f;
    float u0 = 0.f, u1 = 0.f, u2 = 0.f, u3 = 0.f;
#pragma unroll
    for (int t = 0; t < 16; t++) {
        f32x4 v = *(const f32x4*)(buf + l * 68 + 4 * t);
        t0 += v[0]; t1 += v[1]; t2 += v[2]; t3 += v[3];
        u0 += (4 * t     < idx) ? v[0] : 0.f;
        u1 += (4 * t + 1 < idx) ? v[1] : 0.f;
        u2 += (4 * t + 2 < idx) ? v[2] : 0.f;
        u3 += (4 * t + 3 < idx) ? v[3] : 0.f;
    }
    float toth = (t0 + t1) + (t2 + t3);
    float Sh = (u0 + u1) + (u2 + u3);
    float eidx = buf[l * 68 + idx];
    float chh = 5.616f * frcp(toth);
    float yk = fmaf(0.006f, idxf, -BOUND) + chh * Sh;
    float hk = fmaf(chh, eidx, 0.006f);
    hk = (idx == 63) ? (BOUND - yk) : hk;
    LWAIT();

    // ---------------- Phase 8: D/L params via MFMA (1-term), 2 passes -----
    // pass A: params 128..191 -> cols 0..63
#pragma unroll
    for (int m = 0; m < 4; m++) {
        half8 a = *(const half8*)(aW3 + ((m + 8) * 64 + l) * 8);
#pragma unroll
        for (int n = 0; n < 4; n++) {
            f32x4 acc = {0.f, 0.f, 0.f, 0.f};
            acc = __builtin_amdgcn_mfma_f32_16x16x32_f16(a, bhi[n], acc, 0, 0, 0);
            *(f32x4*)(buf + (16 * n + j) * 68 + 16 * m + 4 * g) = acc;
        }
    }
    LWAIT();
    int c0 = (idx > 0) ? (idx - 1) : 0;
    float accd0 = buf[l * 68 + c0];                       // param 127+idx (idx>=1)
    float accd1 = buf[l * 68 + ((idx < 63) ? idx : 63)];  // param 128+idx (idx<=62)
    float acl0  = buf[l * 68 + 63];                       // param 191 (idx==0 case)
    LWAIT();
    // pass B: params 192..255 -> cols 0..63
#pragma unroll
    for (int m = 0; m < 4; m++) {
        half8 a = *(const half8*)(aW3 + ((m + 12) * 64 + l) * 8);
#pragma unroll
        for (int n = 0; n < 4; n++) {
            f32x4 acc = {0.f, 0.f, 0.f, 0.f};
            acc = __builtin_amdgcn_mfma_f32_16x16x32_f16(a, bhi[n], acc, 0, 0, 0);
            *(f32x4*)(buf + (16 * n + j) * 68 + 16 * m + 4 * g) = acc;
        }
    }
    LWAIT();
    float acclB = buf[l * 68 + c0];                       // param 191+idx (idx>=1)
    float accl = (idx == 0) ? acl0 : acclB;

    accd0 += sb3[127 + idx];
    accd1 += sb3[(idx < 63) ? (128 + idx) : 191];
    accl  += sb3[191 + idx];

    // ---------------- Phase 9: tail (verified R2 math) --------------------
    float e0 = fexp2(-fabsf(accd0) * LOG2E);
    float sp0 = fmaxf(accd0, 0.f) + LN2 * flog2(1.f + e0);
    float e1 = fexp2(-fabsf(accd1) * LOG2E);
    float sp1 = fmaxf(accd1, 0.f) + LN2 * flog2(1.f + e1);
    float d0 = (idx == 0)  ? 1.f : (0.001f + sp0);
    float d1 = (idx == 63) ? 1.f : (0.001f + sp1);
    float sig = frcp(1.f + fexp2(-accl * LOG2E));
    float lam = fmaf(0.95f, sig, 0.025f);

    float rwk = frcp(wk);
    float wb = sqrtf(d0 * frcp(d1));
    float wc = fmaf(lam, d0, (1.f - lam) * wb * d1) * wk * frcp(hk);
    float ya = yk, yb = yk + hk;
    float yc = fmaf(1.f - lam, ya, lam * wb * yb) * frcp(fmaf(lam, wb, 1.f - lam));
    float theta = (xc - xk) * rwk;
    bool left = theta <= lam;
    float num = left ? fmaf(ya, lam - theta, wc * yc * theta)
                     : fmaf(wc * yc, 1.f - theta, wb * yb * (theta - lam));
    float den = left ? fmaf(wc, theta, lam - theta)
                     : fmaf(wc, 1.f - theta, wb * (theta - lam));
    float y_in = num * frcp(den);
    float dnum = left ? (wc * lam * (yc - ya))
                      : (wb * wc * (1.f - lam) * (yb - yc));
    float ld_in = LN2 * (flog2(dnum) - 2.f * flog2(fabsf(den)) - flog2(wk));

    if (gown < N) {
        out[gown]     = inside ? y_in : x;
        out[N + gown] = inside ? ld_in : 0.f;
    }
}

extern "C" void kernel_launch(void* const* d_in, const int* in_sizes, int n_in,
                              void* d_out, int out_size, void* d_ws, size_t ws_size,
                              hipStream_t stream) {
    const float* x  = (const float*)d_in[0];
    const float* cx = (const float*)d_in[1];
    const float* W1 = (const float*)d_in[2];
    const float* b1 = (const float*)d_in[3];
    const float* W2 = (const float*)d_in[4];
    const float* b2 = (const float*)d_in[5];
    const float* W3 = (const float*)d_in[6];
    const float* b3 = (const float*)d_in[7];
    int N = in_sizes[0];

    _Float16* aW3 = (_Float16*)d_ws;          // 16*64*8 = 8192 halves
    _Float16* aW2 = aW3 + 16 * 64 * 8;        // 1024 halves
    float* b3s = (float*)(aW2 + 2 * 64 * 8);  // 255 floats
    float* out = (float*)d_out;

    hipLaunchKernelGGL(prep_kernel, dim3(8), dim3(256), 0, stream, W2, W3, b3, aW2, aW3, b3s);
    hipLaunchKernelGGL(spline_kernel, dim3((N + 255) / 256), dim3(256), 0, stream,
                       x, cx, W1, b1, b2, b3s, aW2, aW3, out, N);
}

// Round 5
// 64.281 us; speedup vs baseline: 3.3851x; 1.3736x over previous
//
#include <hip/hip_runtime.h>
#include <math.h>

#define BOUND 3.0f
#define LOG2E 1.4426950408889634f
#define LN2 0.6931471805599453f
#define CINV 0.17806267806267807f   /* 1/5.616 */

typedef _Float16 half8 __attribute__((ext_vector_type(8)));
typedef _Float16 half4 __attribute__((ext_vector_type(4)));
typedef _Float16 half2v __attribute__((ext_vector_type(2)));
typedef float f32x4 __attribute__((ext_vector_type(4)));

__device__ __forceinline__ float fexp2(float x) { return __builtin_amdgcn_exp2f(x); }
__device__ __forceinline__ float flog2(float x) { return __builtin_amdgcn_logf(x); }
__device__ __forceinline__ float frcp(float x)  { return __builtin_amdgcn_rcpf(x); }

// sum of a half2 pair accumulated in f32 via v_dot2_f32_f16
__device__ __forceinline__ float hsum2(half2v a, float c) {
    const half2v ones = {(_Float16)1.f, (_Float16)1.f};
    return __builtin_amdgcn_fdot2(a, ones, c, false);
}

// A-fragments for transposed GEMM C[param][elem], 16x16x32 f16.
// aW3[m][l][t] = W3[8*(l>>4)+t][16m + (l&15)] * (m<8 ? LOG2E : 1)
__global__ void prep_kernel(const float* __restrict__ W2, const float* __restrict__ W3,
                            const float* __restrict__ b3,
                            _Float16* __restrict__ aW2, _Float16* __restrict__ aW3,
                            float* __restrict__ b3s) {
    int tid = blockIdx.x * blockDim.x + threadIdx.x;
    int nth = gridDim.x * blockDim.x;
    for (int i = tid; i < 16 * 64 * 8; i += nth) {
        int t = i & 7, l = (i >> 3) & 63, m = i >> 9;
        int k = 8 * (l >> 4) + t, col = 16 * m + (l & 15);
        float v = (col < 255) ? W3[k * 255 + col] : 0.f;
        if (m < 8) v *= LOG2E;
        aW3[i] = (_Float16)v;
    }
    for (int i = tid; i < 2 * 64 * 8; i += nth) {
        int t = i & 7, l = (i >> 3) & 63, m = i >> 9;
        int k = 8 * (l >> 4) + t, col = 16 * m + (l & 15);
        aW2[i] = (_Float16)W2[k * 32 + col];
    }
    for (int i = tid; i < 255; i += nth)
        b3s[i] = b3[i] * ((i < 128) ? LOG2E : 1.f);
}

__global__ __launch_bounds__(64, 2) void spline_kernel(
    const float* __restrict__ x_in, const float* __restrict__ cond_in,
    const float* __restrict__ W1, const float* __restrict__ b1,
    const float* __restrict__ b2, const float* __restrict__ b3s,
    const _Float16* __restrict__ aW2, const _Float16* __restrict__ aW3,
    float* __restrict__ out, int N) {

    // One wave per workgroup. 16KB buffer, reused per phase:
    //  - f32 view: 64 rows x 64 f32 (256B rows, 16 granules of 16B, XOR-swizzled)
    //  - f16 view: 64 rows x 64 halves (128B rows, 8 granules of 16B, XOR-swizzled)
    __shared__ float sbuf[64 * 64];
    __shared__ float scx[64];

    const int l = threadIdx.x;
    const int j = l & 15, g = l >> 4;
    const int sx = l & 7;          // own-row swizzle key
    const int ksw = j & 7;         // staged-row swizzle key (row = 16n+j, low3 = j&7)
    const int gown = blockIdx.x * 64 + l;
    const int ic = (gown < N) ? gown : (N - 1);

    float* buf = sbuf;
    _Float16* bufh = (_Float16*)sbuf;

    scx[l] = cond_in[ic];
    float x = x_in[ic];

    // ---------------- Phase 1: h1 B-fragments (rank-1) --------------------
    float4 w1a = *(const float4*)(W1 + 8 * g);
    float4 w1b = *(const float4*)(W1 + 8 * g + 4);
    float4 b1a = *(const float4*)(b1 + 8 * g);
    float4 b1b = *(const float4*)(b1 + 8 * g + 4);

    half8 h1hi[4], h1lo[4];
#pragma unroll
    for (int n = 0; n < 4; n++) {
        float c = scx[16 * n + j];
        float h[8];
        h[0] = fmaxf(fmaf(c, w1a.x, b1a.x), 0.f);
        h[1] = fmaxf(fmaf(c, w1a.y, b1a.y), 0.f);
        h[2] = fmaxf(fmaf(c, w1a.z, b1a.z), 0.f);
        h[3] = fmaxf(fmaf(c, w1a.w, b1a.w), 0.f);
        h[4] = fmaxf(fmaf(c, w1b.x, b1b.x), 0.f);
        h[5] = fmaxf(fmaf(c, w1b.y, b1b.y), 0.f);
        h[6] = fmaxf(fmaf(c, w1b.z, b1b.z), 0.f);
        h[7] = fmaxf(fmaf(c, w1b.w, b1b.w), 0.f);
#pragma unroll
        for (int t = 0; t < 8; t++) {
            _Float16 hi = (_Float16)h[t];
            h1hi[n][t] = hi;
            h1lo[n][t] = (_Float16)(h[t] - (float)hi);
        }
    }

    // ---------------- Phase 2: MLP2 via MFMA, split h2 -> LDS (f16) -------
    half8 a2[2];
    a2[0] = *(const half8*)(aW2 + (0 * 64 + l) * 8);
    a2[1] = *(const half8*)(aW2 + (1 * 64 + l) * 8);

#pragma unroll
    for (int m = 0; m < 2; m++) {
        float4 bb = *(const float4*)(b2 + 16 * m + 4 * g);
        f32x4 binit = {bb.x, bb.y, bb.z, bb.w};
#pragma unroll
        for (int n = 0; n < 4; n++) {
            f32x4 acc = binit;
            acc = __builtin_amdgcn_mfma_f32_16x16x32_f16(a2[m], h1lo[n], acc, 0, 0, 0);
            acc = __builtin_amdgcn_mfma_f32_16x16x32_f16(a2[m], h1hi[n], acc, 0, 0, 0);
            float v0 = fmaxf(acc[0], 0.f), v1 = fmaxf(acc[1], 0.f);
            float v2 = fmaxf(acc[2], 0.f), v3 = fmaxf(acc[3], 0.f);
            _Float16 p0 = (_Float16)v0, p1 = (_Float16)v1, p2 = (_Float16)v2, p3 = (_Float16)v3;
            half4 hv = {p0, p1, p2, p3};
            half4 lv = {(_Float16)(v0 - (float)p0), (_Float16)(v1 - (float)p1),
                        (_Float16)(v2 - (float)p2), (_Float16)(v3 - (float)p3)};
            int rb = (16 * n + j) * 64;
            // hi at halves 16m+4g (granule 2m+(g>>1)), lo at +32 (granule 4+..)
            *(half4*)(bufh + rb + (((2 * m + (g >> 1)) ^ ksw) << 3) + ((g & 1) << 2)) = hv;
            *(half4*)(bufh + rb + (((4 + 2 * m + (g >> 1)) ^ ksw) << 3) + ((g & 1) << 2)) = lv;
        }
    }

    // ---------------- Phase 3: h2 B-fragments -----------------------------
    half8 bhi[4], blo[4];
#pragma unroll
    for (int n = 0; n < 4; n++) {
        int rb = (16 * n + j) * 64;
        bhi[n] = *(const half8*)(bufh + rb + ((g ^ ksw) << 3));
        blo[n] = *(const half8*)(bufh + rb + (((4 + g) ^ ksw) << 3));
    }

    bool inside = (x >= -BOUND) && (x <= BOUND);
    float xc = fminf(fmaxf(x, -BOUND), BOUND);

    // ---------------- Phase 4: W logits -> exp2 -> LDS (f32) --------------
#pragma unroll
    for (int m = 0; m < 4; m++) {
        half8 a = *(const half8*)(aW3 + (m * 64 + l) * 8);
        float4 bb = *(const float4*)(b3s + 16 * m + 4 * g);
        f32x4 binit = {bb.x, bb.y, bb.z, bb.w};
#pragma unroll
        for (int n = 0; n < 4; n++) {
            f32x4 acc = binit;
            acc = __builtin_amdgcn_mfma_f32_16x16x32_f16(a, blo[n], acc, 0, 0, 0);
            acc = __builtin_amdgcn_mfma_f32_16x16x32_f16(a, bhi[n], acc, 0, 0, 0);
            f32x4 e = {fexp2(acc[0]), fexp2(acc[1]), fexp2(acc[2]), fexp2(acc[3])};
            *(f32x4*)(buf + (16 * n + j) * 64 + (((4 * m + g) ^ ksw) << 2)) = e;
        }
    }

    // ---------------- Phase 5: hierarchical W scan (f32-exact) ------------
    int idx; float idxf, xk, wk;
    {
        f32x4 wv[16];
#pragma unroll
        for (int t = 0; t < 16; t++)
            wv[t] = *(const f32x4*)(buf + l * 64 + (((t ^ sx)) << 2));
        float G[16];
        float run = 0.f;
#pragma unroll
        for (int t = 0; t < 16; t++) {
            run += (wv[t][0] + wv[t][1]) + (wv[t][2] + wv[t][3]);
            G[t] = run;
        }
        float tot = G[15];
        float rcptot = frcp(tot);
        float rr = (xc + BOUND) * tot * CINV;
        float dr1 = 0.0010683761f * tot;
        float dr4 = 4.f * dr1;
        float r = rr, Gsel = 0.f;
        int qidx = 0;
#pragma unroll
        for (int t = 0; t < 15; t++) {
            r -= dr4;
            bool c = (G[t] <= r);
            qidx += c ? 1 : 0;
            Gsel = c ? G[t] : Gsel;
        }
        // fine: 4 exps of chosen group (exact f32 values already in wv)
        f32x4 fv = wv[0];
#pragma unroll
        for (int t = 1; t < 16; t++) fv = (qidx == t) ? wv[t] : fv;
        // note: wv[t] holds group (t ^ sx ^ sx) = t; indexing by qidx is correct
        float e0 = fv[0], e1 = fv[1], e2 = fv[2], e3 = fv[3];
        float qf = (float)qidx;
        float rq = fmaf(-qf, dr4, rr);
        float p1 = Gsel + e0, p2 = p1 + e1, p3 = p2 + e2;
        bool c1 = (p1 <= rq - dr1);
        bool c2 = (p2 <= fmaf(-2.f, dr1, rq));
        bool c3 = (p3 <= fmaf(-3.f, dr1, rq));
        idx = 4 * qidx + (c1 ? 1 : 0) + (c2 ? 1 : 0) + (c3 ? 1 : 0);
        float Pk = c1 ? p1 : Gsel; Pk = c2 ? p2 : Pk; Pk = c3 ? p3 : Pk;
        float ek = c1 ? e1 : e0;   ek = c2 ? e2 : ek; ek = c3 ? e3 : ek;
        idxf = (float)idx;
        xk = fmaf(0.006f, idxf, -BOUND) + 5.616f * Pk * rcptot;
        wk = fmaf(5.616f * rcptot, ek, 0.006f);
        wk = (idx == 63) ? (BOUND - xk) : wk;
    }

    // ---------------- Phase 6: H logits -> exp2 -> LDS (f16, 1-term) ------
#pragma unroll
    for (int m = 0; m < 4; m++) {
        half8 a = *(const half8*)(aW3 + ((m + 4) * 64 + l) * 8);
        float4 bb = *(const float4*)(b3s + 64 + 16 * m + 4 * g);
        f32x4 binit = {bb.x, bb.y, bb.z, bb.w};
#pragma unroll
        for (int n = 0; n < 4; n++) {
            f32x4 acc = binit;
            acc = __builtin_amdgcn_mfma_f32_16x16x32_f16(a, bhi[n], acc, 0, 0, 0);
            half4 e = {(_Float16)fexp2(acc[0]), (_Float16)fexp2(acc[1]),
                       (_Float16)fexp2(acc[2]), (_Float16)fexp2(acc[3])};
            *(half4*)(bufh + (16 * n + j) * 64 +
                      (((2 * m + (g >> 1)) ^ ksw) << 3) + ((g & 1) << 2)) = e;
        }
    }

    // ---------------- Phase 7: H selection (fdot2 group sums) -------------
    float yk, hk;
    {
        int qh = idx >> 2, rh = idx & 3;
        float toth = 0.f, Gq = 0.f;
#pragma unroll
        for (int t = 0; t < 8; t++) {
            half8 hv = *(const half8*)(bufh + l * 64 + ((t ^ sx) << 3));
            half2v* hp = (half2v*)&hv;
            float gs0 = hsum2(hp[0], hsum2(hp[1], 0.f));
            float gs1 = hsum2(hp[2], hsum2(hp[3], 0.f));
            toth += gs0 + gs1;
            Gq += (2 * t < qh) ? gs0 : 0.f;
            Gq += (2 * t + 1 < qh) ? gs1 : 0.f;
        }
        // fine: re-read chosen group's 4 halves (8B)
        half4 fv = *(const half4*)(bufh + l * 64 + (((qh >> 1) ^ sx) << 3) + ((qh & 1) << 2));
        float f0 = (float)fv[0], f1 = (float)fv[1], f2 = (float)fv[2], f3 = (float)fv[3];
        float Sh = Gq;
        Sh += (rh >= 1) ? f0 : 0.f;
        Sh += (rh >= 2) ? f1 : 0.f;
        Sh += (rh >= 3) ? f2 : 0.f;
        float x01 = (rh & 1) ? f1 : f0;
        float x23 = (rh & 1) ? f3 : f2;
        float eidx = (rh & 2) ? x23 : x01;
        float chh = 5.616f * frcp(toth);
        yk = fmaf(0.006f, idxf, -BOUND) + chh * Sh;
        hk = fmaf(chh, eidx, 0.006f);
        hk = (idx == 63) ? (BOUND - yk) : hk;
    }

    // ---------------- Phase 8: D/L via MFMA, f32-staged (1-term) ----------
    int c0 = (idx > 0) ? (idx - 1) : 0;
    float accd0, accd1, accl;
    {
        // pass A: params 128..191 (col c = param 128+c)
#pragma unroll
        for (int m = 0; m < 4; m++) {
            half8 a = *(const half8*)(aW3 + ((m + 8) * 64 + l) * 8);
#pragma unroll
            for (int n = 0; n < 4; n++) {
                f32x4 acc = {0.f, 0.f, 0.f, 0.f};
                acc = __builtin_amdgcn_mfma_f32_16x16x32_f16(a, bhi[n], acc, 0, 0, 0);
                *(f32x4*)(buf + (16 * n + j) * 64 + (((4 * m + g) ^ ksw) << 2)) = acc;
            }
        }
        accd0 = buf[l * 64 + (((c0 >> 2) ^ sx) << 2) + (c0 & 3)];          // param 127+idx
        accd1 = buf[l * 64 + (((idx >> 2) ^ sx) << 2) + (idx & 3)];        // param 128+idx
        float acl0 = buf[l * 64 + ((15 ^ sx) << 2) + 3];                   // param 191
        // pass B: params 192..255
#pragma unroll
        for (int m = 0; m < 4; m++) {
            half8 a = *(const half8*)(aW3 + ((m + 12) * 64 + l) * 8);
#pragma unroll
            for (int n = 0; n < 4; n++) {
                f32x4 acc = {0.f, 0.f, 0.f, 0.f};
                acc = __builtin_amdgcn_mfma_f32_16x16x32_f16(a, bhi[n], acc, 0, 0, 0);
                *(f32x4*)(buf + (16 * n + j) * 64 + (((4 * m + g) ^ ksw) << 2)) = acc;
            }
        }
        float aclB = buf[l * 64 + (((c0 >> 2) ^ sx) << 2) + (c0 & 3)];     // param 191+idx
        accd0 += b3s[127 + idx];
        accd1 += b3s[(idx < 63) ? (128 + idx) : 191];
        accl = ((idx == 0) ? acl0 : aclB) + b3s[191 + idx];
    }

    // ---------------- Phase 9: tail ---------------------------------------
    float e0t = fexp2(-fabsf(accd0) * LOG2E);
    float sp0 = fmaxf(accd0, 0.f) + LN2 * flog2(1.f + e0t);
    float e1t = fexp2(-fabsf(accd1) * LOG2E);
    float sp1 = fmaxf(accd1, 0.f) + LN2 * flog2(1.f + e1t);
    float d0 = (idx == 0)  ? 1.f : (0.001f + sp0);
    float d1 = (idx == 63) ? 1.f : (0.001f + sp1);
    float sig = frcp(1.f + fexp2(-accl * LOG2E));
    float lam = fmaf(0.95f, sig, 0.025f);

    float rwk = frcp(wk);
    float wb = sqrtf(d0 * frcp(d1));
    float wc = fmaf(lam, d0, (1.f - lam) * wb * d1) * wk * frcp(hk);
    float ya = yk, yb = yk + hk;
    float yc = fmaf(1.f - lam, ya, lam * wb * yb) * frcp(fmaf(lam, wb, 1.f - lam));
    float theta = (xc - xk) * rwk;
    bool left = theta <= lam;
    float num = left ? fmaf(ya, lam - theta, wc * yc * theta)
                     : fmaf(wc * yc, 1.f - theta, wb * yb * (theta - lam));
    float den = left ? fmaf(wc, theta, lam - theta)
                     : fmaf(wc, 1.f - theta, wb * (theta - lam));
    float y_in = num * frcp(den);
    float dnum = left ? (wc * lam * (yc - ya))
                      : (wb * wc * (1.f - lam) * (yb - yc));
    float ld_in = LN2 * (flog2(dnum) - 2.f * flog2(fabsf(den)) - flog2(wk));

    if (gown < N) {
        out[gown]     = inside ? y_in : x;
        out[N + gown] = inside ? ld_in : 0.f;
    }
}

extern "C" void kernel_launch(void* const* d_in, const int* in_sizes, int n_in,
                              void* d_out, int out_size, void* d_ws, size_t ws_size,
                              hipStream_t stream) {
    const float* x  = (const float*)d_in[0];
    const float* cx = (const float*)d_in[1];
    const float* W1 = (const float*)d_in[2];
    const float* b1 = (const float*)d_in[3];
    const float* W2 = (const float*)d_in[4];
    const float* b2 = (const float*)d_in[5];
    const float* W3 = (const float*)d_in[6];
    const float* b3 = (const float*)d_in[7];
    int N = in_sizes[0];

    _Float16* aW3 = (_Float16*)d_ws;          // 16*64*8 halves
    _Float16* aW2 = aW3 + 16 * 64 * 8;        // 1024 halves
    float* b3s = (float*)(aW2 + 2 * 64 * 8);  // 255 floats
    float* out = (float*)d_out;

    hipLaunchKernelGGL(prep_kernel, dim3(8), dim3(256), 0, stream, W2, W3, b3, aW2, aW3, b3s);
    hipLaunchKernelGGL(spline_kernel, dim3((N + 63) / 64), dim3(64), 0, stream,
                       x, cx, W1, b1, b2, b3s, aW2, aW3, out, N);
}

// Round 6
// 59.429 us; speedup vs baseline: 3.6614x; 1.0816x over previous
//
#include <hip/hip_runtime.h>
#include <math.h>

#define BOUND 3.0f
#define LOG2E 1.4426950408889634f
#define LN2 0.6931471805599453f
#define CINV 0.17806267806267807f   /* 1/5.616 */

typedef _Float16 half8 __attribute__((ext_vector_type(8)));
typedef _Float16 half4 __attribute__((ext_vector_type(4)));
typedef _Float16 half2v __attribute__((ext_vector_type(2)));
typedef float f32x4 __attribute__((ext_vector_type(4)));

__device__ __forceinline__ float fexp2(float x) { return __builtin_amdgcn_exp2f(x); }
__device__ __forceinline__ float flog2(float x) { return __builtin_amdgcn_logf(x); }
__device__ __forceinline__ float frcp(float x)  { return __builtin_amdgcn_rcpf(x); }

__device__ __forceinline__ float hsum2(half2v a, float c) {
    const half2v ones = {(_Float16)1.f, (_Float16)1.f};
    return __builtin_amdgcn_fdot2(a, ones, c, false);
}

// A-fragments for transposed GEMM C[param][elem], 16x16x32 f16.
// aW3[m][l][t] = W3[8*(l>>4)+t][16m + (l&15)] * (m<8 ? LOG2E : 1)
__global__ void prep_kernel(const float* __restrict__ W2, const float* __restrict__ W3,
                            const float* __restrict__ b3,
                            _Float16* __restrict__ aW2, _Float16* __restrict__ aW3,
                            float* __restrict__ b3s) {
    int tid = blockIdx.x * blockDim.x + threadIdx.x;
    int nth = gridDim.x * blockDim.x;
    for (int i = tid; i < 16 * 64 * 8; i += nth) {
        int t = i & 7, l = (i >> 3) & 63, m = i >> 9;
        int k = 8 * (l >> 4) + t, col = 16 * m + (l & 15);
        float v = (col < 255) ? W3[k * 255 + col] : 0.f;
        if (m < 8) v *= LOG2E;
        aW3[i] = (_Float16)v;
    }
    for (int i = tid; i < 2 * 64 * 8; i += nth) {
        int t = i & 7, l = (i >> 3) & 63, m = i >> 9;
        int k = 8 * (l >> 4) + t, col = 16 * m + (l & 15);
        aW2[i] = (_Float16)W2[k * 32 + col];
    }
    for (int i = tid; i < 255; i += nth)
        b3s[i] = b3[i] * ((i < 128) ? LOG2E : 1.f);
}

__global__ __launch_bounds__(64, 4) void spline_kernel(
    const float* __restrict__ x_in, const float* __restrict__ cond_in,
    const float* __restrict__ W1, const float* __restrict__ b1,
    const float* __restrict__ b2, const float* __restrict__ b3s,
    const _Float16* __restrict__ aW2, const _Float16* __restrict__ aW3,
    float* __restrict__ out, int N) {

    // One wave per workgroup. Single 8KB buffer, reused per phase, relying
    // on same-wave in-order DS semantics (no barriers, uniform exec).
    //  f32 view: 64 rows x 32 f32 (128B rows, 8 granules, XOR-swizzled)
    //  f16 view: 64 rows x 64 halves (128B rows, 8 granules, XOR-swizzled)
    __shared__ float sbuf[64 * 32];

    const int l = threadIdx.x;
    const int j = l & 15, g = l >> 4;
    const int sx = l & 7;
    const int ksw = j & 7;
    const int gown = blockIdx.x * 64 + l;
    const int ic = (gown < N) ? gown : (N - 1);

    float* buf = sbuf;
    _Float16* bufh = (_Float16*)sbuf;

    float cx = cond_in[ic];
    float x = x_in[ic];

    // ---------------- Phase 1: h1 B-fragments (rank-1) --------------------
    float4 w1a = *(const float4*)(W1 + 8 * g);
    float4 w1b = *(const float4*)(W1 + 8 * g + 4);
    float4 b1a = *(const float4*)(b1 + 8 * g);
    float4 b1b = *(const float4*)(b1 + 8 * g + 4);

    half8 h1hi[4], h1lo[4];
#pragma unroll
    for (int n = 0; n < 4; n++) {
        float c = __shfl(cx, 16 * n + j, 64);
        float h[8];
        h[0] = fmaxf(fmaf(c, w1a.x, b1a.x), 0.f);
        h[1] = fmaxf(fmaf(c, w1a.y, b1a.y), 0.f);
        h[2] = fmaxf(fmaf(c, w1a.z, b1a.z), 0.f);
        h[3] = fmaxf(fmaf(c, w1a.w, b1a.w), 0.f);
        h[4] = fmaxf(fmaf(c, w1b.x, b1b.x), 0.f);
        h[5] = fmaxf(fmaf(c, w1b.y, b1b.y), 0.f);
        h[6] = fmaxf(fmaf(c, w1b.z, b1b.z), 0.f);
        h[7] = fmaxf(fmaf(c, w1b.w, b1b.w), 0.f);
#pragma unroll
        for (int t = 0; t < 8; t++) {
            _Float16 hi = (_Float16)h[t];
            h1hi[n][t] = hi;
            h1lo[n][t] = (_Float16)(h[t] - (float)hi);
        }
    }

    // ---------------- Phase 2: MLP2 via MFMA, split h2 -> LDS (f16) -------
    half8 a2[2];
    a2[0] = *(const half8*)(aW2 + (0 * 64 + l) * 8);
    a2[1] = *(const half8*)(aW2 + (1 * 64 + l) * 8);

#pragma unroll
    for (int m = 0; m < 2; m++) {
        float4 bb = *(const float4*)(b2 + 16 * m + 4 * g);
        f32x4 binit = {bb.x, bb.y, bb.z, bb.w};
#pragma unroll
        for (int n = 0; n < 4; n++) {
            f32x4 acc = binit;
            acc = __builtin_amdgcn_mfma_f32_16x16x32_f16(a2[m], h1lo[n], acc, 0, 0, 0);
            acc = __builtin_amdgcn_mfma_f32_16x16x32_f16(a2[m], h1hi[n], acc, 0, 0, 0);
            float v0 = fmaxf(acc[0], 0.f), v1 = fmaxf(acc[1], 0.f);
            float v2 = fmaxf(acc[2], 0.f), v3 = fmaxf(acc[3], 0.f);
            _Float16 p0 = (_Float16)v0, p1 = (_Float16)v1, p2 = (_Float16)v2, p3 = (_Float16)v3;
            half4 hv = {p0, p1, p2, p3};
            half4 lv = {(_Float16)(v0 - (float)p0), (_Float16)(v1 - (float)p1),
                        (_Float16)(v2 - (float)p2), (_Float16)(v3 - (float)p3)};
            int rb = (16 * n + j) * 64;
            *(half4*)(bufh + rb + (((2 * m + (g >> 1)) ^ ksw) << 3) + ((g & 1) << 2)) = hv;
            *(half4*)(bufh + rb + (((4 + 2 * m + (g >> 1)) ^ ksw) << 3) + ((g & 1) << 2)) = lv;
        }
    }

    // ---------------- Phase 3: h2 B-fragments -----------------------------
    half8 bhi[4], blo[4];
#pragma unroll
    for (int n = 0; n < 4; n++) {
        int rb = (16 * n + j) * 64;
        bhi[n] = *(const half8*)(bufh + rb + ((g ^ ksw) << 3));
        blo[n] = *(const half8*)(bufh + rb + (((4 + g) ^ ksw) << 3));
    }

    bool inside = (x >= -BOUND) && (x <= BOUND);
    float xc = fminf(fmaxf(x, -BOUND), BOUND);

    // ---------------- Phase 4: W logits -> exp2 -> LDS (f32, 2 rounds) ----
    f32x4 wv[16];
#pragma unroll
    for (int s = 0; s < 2; s++) {
#pragma unroll
        for (int mm = 0; mm < 2; mm++) {
            int m = 2 * s + mm;
            half8 a = *(const half8*)(aW3 + (m * 64 + l) * 8);
            float4 bb = *(const float4*)(b3s + 16 * m + 4 * g);
            f32x4 binit = {bb.x, bb.y, bb.z, bb.w};
#pragma unroll
            for (int n = 0; n < 4; n++) {
                f32x4 acc = binit;
                acc = __builtin_amdgcn_mfma_f32_16x16x32_f16(a, blo[n], acc, 0, 0, 0);
                acc = __builtin_amdgcn_mfma_f32_16x16x32_f16(a, bhi[n], acc, 0, 0, 0);
                f32x4 e = {fexp2(acc[0]), fexp2(acc[1]), fexp2(acc[2]), fexp2(acc[3])};
                *(f32x4*)(buf + (16 * n + j) * 32 + (((4 * mm + g) ^ ksw) << 2)) = e;
            }
        }
#pragma unroll
        for (int t = 0; t < 8; t++)
            wv[8 * s + t] = *(const f32x4*)(buf + l * 32 + ((t ^ sx) << 2));
    }

    // ---------------- Phase 5: hierarchical W scan (f32-exact) ------------
    int idx; float idxf, xk, wk;
    {
        float G[16];
        float run = 0.f;
#pragma unroll
        for (int t = 0; t < 16; t++) {
            run += (wv[t][0] + wv[t][1]) + (wv[t][2] + wv[t][3]);
            G[t] = run;
        }
        float tot = G[15];
        float rcptot = frcp(tot);
        float rr = (xc + BOUND) * tot * CINV;
        float dr1 = 0.0010683761f * tot;
        float dr4 = 4.f * dr1;
        float r = rr, Gsel = 0.f;
        int qidx = 0;
#pragma unroll
        for (int t = 0; t < 15; t++) {
            r -= dr4;
            bool c = (G[t] <= r);
            qidx += c ? 1 : 0;
            Gsel = c ? G[t] : Gsel;
        }
        f32x4 fv = wv[0];
#pragma unroll
        for (int t = 1; t < 16; t++) fv = (qidx == t) ? wv[t] : fv;
        float e0 = fv[0], e1 = fv[1], e2 = fv[2], e3 = fv[3];
        float qf = (float)qidx;
        float rq = fmaf(-qf, dr4, rr);
        float p1 = Gsel + e0, p2 = p1 + e1, p3 = p2 + e2;
        bool c1 = (p1 <= rq - dr1);
        bool c2 = (p2 <= fmaf(-2.f, dr1, rq));
        bool c3 = (p3 <= fmaf(-3.f, dr1, rq));
        idx = 4 * qidx + (c1 ? 1 : 0) + (c2 ? 1 : 0) + (c3 ? 1 : 0);
        float Pk = c1 ? p1 : Gsel; Pk = c2 ? p2 : Pk; Pk = c3 ? p3 : Pk;
        float ek = c1 ? e1 : e0;   ek = c2 ? e2 : ek; ek = c3 ? e3 : ek;
        idxf = (float)idx;
        xk = fmaf(0.006f, idxf, -BOUND) + 5.616f * Pk * rcptot;
        wk = fmaf(5.616f * rcptot, ek, 0.006f);
        wk = (idx == 63) ? (BOUND - xk) : wk;
    }

    // ---------------- Phase 6: H logits -> exp2 -> LDS (f16, 1-term) ------
#pragma unroll
    for (int m = 0; m < 4; m++) {
        half8 a = *(const half8*)(aW3 + ((m + 4) * 64 + l) * 8);
        float4 bb = *(const float4*)(b3s + 64 + 16 * m + 4 * g);
        f32x4 binit = {bb.x, bb.y, bb.z, bb.w};
#pragma unroll
        for (int n = 0; n < 4; n++) {
            f32x4 acc = binit;
            acc = __builtin_amdgcn_mfma_f32_16x16x32_f16(a, bhi[n], acc, 0, 0, 0);
            half4 e = {(_Float16)fexp2(acc[0]), (_Float16)fexp2(acc[1]),
                       (_Float16)fexp2(acc[2]), (_Float16)fexp2(acc[3])};
            *(half4*)(bufh + (16 * n + j) * 64 +
                      (((2 * m + (g >> 1)) ^ ksw) << 3) + ((g & 1) << 2)) = e;
        }
    }

    // ---------------- Phase 7: H selection (fdot2 group sums) -------------
    float yk, hk;
    {
        int qh = idx >> 2, rh = idx & 3;
        float toth = 0.f, Gq = 0.f;
#pragma unroll
        for (int t = 0; t < 8; t++) {
            half8 hv = *(const half8*)(bufh + l * 64 + ((t ^ sx) << 3));
            half2v* hp = (half2v*)&hv;
            float gs0 = hsum2(hp[0], hsum2(hp[1], 0.f));
            float gs1 = hsum2(hp[2], hsum2(hp[3], 0.f));
            toth += gs0 + gs1;
            Gq += (2 * t < qh) ? gs0 : 0.f;
            Gq += (2 * t + 1 < qh) ? gs1 : 0.f;
        }
        half4 fv = *(const half4*)(bufh + l * 64 + (((qh >> 1) ^ sx) << 3) + ((qh & 1) << 2));
        float f0 = (float)fv[0], f1 = (float)fv[1], f2 = (float)fv[2], f3 = (float)fv[3];
        float Sh = Gq;
        Sh += (rh >= 1) ? f0 : 0.f;
        Sh += (rh >= 2) ? f1 : 0.f;
        Sh += (rh >= 3) ? f2 : 0.f;
        float x01 = (rh & 1) ? f1 : f0;
        float x23 = (rh & 1) ? f3 : f2;
        float eidx = (rh & 2) ? x23 : x01;
        float chh = 5.616f * frcp(toth);
        yk = fmaf(0.006f, idxf, -BOUND) + chh * Sh;
        hk = fmaf(chh, eidx, 0.006f);
        hk = (idx == 63) ? (BOUND - yk) : hk;
    }

    // ---------------- Phase 8: D/L via MFMA, f32-staged, 4 rounds ---------
    // Round s stages params 128+32s .. 159+32s into the 8KB buffer.
    // Needed: P0 = param 127+idx (col idx-1), P1 = param 128+idx (col idx),
    //         PL = param 191+idx (col idx-1 of rounds 2/3; col 31 of round 1
    //              when idx==0).
    const int c0 = (idx > 0) ? (idx - 1) : 0;
    const int rc0a = (c0 < 32) ? c0 : 31;
    const int rc0b = (c0 >= 32) ? (c0 - 32) : 0;
    const int rc1a = (idx < 32) ? idx : 31;
    const int rc1b = (idx >= 32) ? (idx - 32) : 0;
    float v0a, v0b, v1a, v1b, vl191, vla, vlb;
#pragma unroll
    for (int s = 0; s < 4; s++) {
#pragma unroll
        for (int mm = 0; mm < 2; mm++) {
            half8 a = *(const half8*)(aW3 + ((8 + 2 * s + mm) * 64 + l) * 8);
#pragma unroll
            for (int n = 0; n < 4; n++) {
                f32x4 acc = {0.f, 0.f, 0.f, 0.f};
                acc = __builtin_amdgcn_mfma_f32_16x16x32_f16(a, bhi[n], acc, 0, 0, 0);
                *(f32x4*)(buf + (16 * n + j) * 32 + (((4 * mm + g) ^ ksw) << 2)) = acc;
            }
        }
        if (s == 0) {
            v0a = buf[l * 32 + (((rc0a >> 2) ^ sx) << 2) + (rc0a & 3)];
            v1a = buf[l * 32 + (((rc1a >> 2) ^ sx) << 2) + (rc1a & 3)];
        } else if (s == 1) {
            v0b = buf[l * 32 + (((rc0b >> 2) ^ sx) << 2) + (rc0b & 3)];
            v1b = buf[l * 32 + (((rc1b >> 2) ^ sx) << 2) + (rc1b & 3)];
            vl191 = buf[l * 32 + ((7 ^ sx) << 2) + 3];   // param 191 (col 31)
        } else if (s == 2) {
            vla = buf[l * 32 + (((rc0a >> 2) ^ sx) << 2) + (rc0a & 3)];
        } else {
            vlb = buf[l * 32 + (((rc0b >> 2) ^ sx) << 2) + (rc0b & 3)];
        }
    }
    float accd0 = ((c0 < 32) ? v0a : v0b) + b3s[127 + idx];
    float accd1 = ((idx < 32) ? v1a : v1b) + b3s[(idx < 63) ? (128 + idx) : 191];
    float lsel = (c0 < 32) ? vla : vlb;
    float accl = ((idx == 0) ? vl191 : lsel) + b3s[191 + idx];

    // ---------------- Phase 9: tail ---------------------------------------
    float e0t = fexp2(-fabsf(accd0) * LOG2E);
    float sp0 = fmaxf(accd0, 0.f) + LN2 * flog2(1.f + e0t);
    float e1t = fexp2(-fabsf(accd1) * LOG2E);
    float sp1 = fmaxf(accd1, 0.f) + LN2 * flog2(1.f + e1t);
    float d0 = (idx == 0)  ? 1.f : (0.001f + sp0);
    float d1 = (idx == 63) ? 1.f : (0.001f + sp1);
    float sig = frcp(1.f + fexp2(-accl * LOG2E));
    float lam = fmaf(0.95f, sig, 0.025f);

    float rwk = frcp(wk);
    float wb = sqrtf(d0 * frcp(d1));
    float wc = fmaf(lam, d0, (1.f - lam) * wb * d1) * wk * frcp(hk);
    float ya = yk, yb = yk + hk;
    float yc = fmaf(1.f - lam, ya, lam * wb * yb) * frcp(fmaf(lam, wb, 1.f - lam));
    float theta = (xc - xk) * rwk;
    bool left = theta <= lam;
    float num = left ? fmaf(ya, lam - theta, wc * yc * theta)
                     : fmaf(wc * yc, 1.f - theta, wb * yb * (theta - lam));
    float den = left ? fmaf(wc, theta, lam - theta)
                     : fmaf(wc, 1.f - theta, wb * (theta - lam));
    float y_in = num * frcp(den);
    float dnum = left ? (wc * lam * (yc - ya))
                      : (wb * wc * (1.f - lam) * (yb - yc));
    float ld_in = LN2 * (flog2(dnum) - 2.f * flog2(fabsf(den)) - flog2(wk));

    if (gown < N) {
        out[gown]     = inside ? y_in : x;
        out[N + gown] = inside ? ld_in : 0.f;
    }
}

extern "C" void kernel_launch(void* const* d_in, const int* in_sizes, int n_in,
                              void* d_out, int out_size, void* d_ws, size_t ws_size,
                              hipStream_t stream) {
    const float* x  = (const float*)d_in[0];
    const float* cx = (const float*)d_in[1];
    const float* W1 = (const float*)d_in[2];
    const float* b1 = (const float*)d_in[3];
    const float* W2 = (const float*)d_in[4];
    const float* b2 = (const float*)d_in[5];
    const float* W3 = (const float*)d_in[6];
    const float* b3 = (const float*)d_in[7];
    int N = in_sizes[0];

    _Float16* aW3 = (_Float16*)d_ws;          // 16*64*8 halves
    _Float16* aW2 = aW3 + 16 * 64 * 8;        // 1024 halves
    float* b3s = (float*)(aW2 + 2 * 64 * 8);  // 255 floats
    float* out = (float*)d_out;

    hipLaunchKernelGGL(prep_kernel, dim3(8), dim3(256), 0, stream, W2, W3, b3, aW2, aW3, b3s);
    hipLaunchKernelGGL(spline_kernel, dim3((N + 63) / 64), dim3(64), 0, stream,
                       x, cx, W1, b1, b2, b3s, aW2, aW3, out, N);
}